// Round 3
// baseline (116.804 us; speedup 1.0000x reference)
//
#include <hip/hip_runtime.h>
#include <math.h>

#define EPS 1e-4f

__device__ __forceinline__ float wave_sum(float v) {
    for (int m = 1; m < 64; m <<= 1)
        v += __shfl_xor(v, m, 64);
    return v;
}

// tanh(x) = 1 - 2/(exp(2x)+1); exp via v_exp_f32, div via v_rcp_f32.
// Saturates correctly for large |x| through inf/0 arithmetic.
__device__ __forceinline__ float fast_tanh(float x) {
    float e = __expf(2.0f * x);
    return fmaf(-2.0f, __builtin_amdgcn_rcpf(e + 1.0f), 1.0f);
}

// One kernel does everything:
//  - block = 4 waves = 4 adjacent j for one (tensor, b)
//  - prologue: compute Y[t][k] = (w0*x[2k]+w1*x[2k+1])/(|x|^2+EPS) into LDS
//              (redundant across the 32 blocks of a (tensor,b) — 4% of loop cost),
//              stage xj[w][t] = emb[tok_t*128 + j_w] into LDS
//  - main loop: 2-layer strided-conv RNN scan, state in wave-private LDS
//  - epilogue: running-max values dotted with lin_w, wave-reduced, atomicAdd
//              into 32 score slots; last block applies bias + log_softmax.
__global__ __launch_bounds__(256) void rnn_fused(
    const int* __restrict__ q, const int* __restrict__ a,
    const float* __restrict__ emb, const float* __restrict__ cw,
    const float* __restrict__ cb, const float* __restrict__ lw,
    const float* __restrict__ lb, float* __restrict__ acc,
    int* __restrict__ counter, float* __restrict__ out)
{
    __shared__ float Ylds[64][64];   // 16 KB
    __shared__ float XJ[4][64];      //  1 KB
    __shared__ float H1[4][128];     //  2 KB
    __shared__ float H2[4][128];     //  2 KB
    __shared__ int lastflag;

    int w    = threadIdx.x >> 6;
    int lane = threadIdx.x & 63;
    int wid  = blockIdx.x * 4 + w;            // [0,4096)
    int tensor = wid >> 11;
    int b      = (wid >> 7) & 15;
    int j      = wid & 127;
    const int* toks = (tensor ? a : q) + b * 64;
    float w10 = cw[0], w11 = cw[1], b1 = cb[0];
    float w20 = cw[2], w21 = cw[3], b2 = cb[1];

    // ---- Phase A: Y (wave w handles t = w*16 .. w*16+15) ----
    for (int i = 0; i < 16; ++i) {
        int t = w * 16 + i;
        int tok = toks[t];
        float2 xv = ((const float2*)(emb + (size_t)tok * 128))[lane];
        float s = wave_sum(fmaf(xv.x, xv.x, xv.y * xv.y)) + EPS;
        Ylds[t][lane] = fmaf(w10, xv.x, w11 * xv.y) * __builtin_amdgcn_rcpf(s);
    }
    // ---- Phase B: xj table + state init ----
    XJ[w][lane] = emb[(size_t)toks[lane] * 128 + j];
    H1[w][lane] = 0.f; H1[w][lane + 64] = 0.f;
    H2[w][lane] = 0.f; H2[w][lane + 64] = 0.f;
    __syncthreads();

    // ---- Main scan ----
    float mlo = -1e30f, mhi = -1e30f;
    float* h1b = &H1[w][0];
    float* h2b = &H2[w][0];
    const float* Yp = &Ylds[0][lane];
    int l2 = 2 * lane;

    #pragma unroll 2
    for (int t = 0; t < 64; ++t) {
        float yv = Yp[t * 64];
        float xj = XJ[w][t];
        float2 o1 = *(const float2*)(h1b + l2);   // old h1[2l], h1[2l+1]
        float2 o2 = *(const float2*)(h2b + l2);   // old h2[2l], h2[2l+1]
        asm volatile("" ::: "memory");
        float n1lo = fast_tanh(fmaf(yv, xj, b1));
        float n1hi = fast_tanh(fmaf(w10, o1.x, fmaf(w11, o1.y, b1)));
        h1b[lane]      = n1lo;
        h1b[lane + 64] = n1hi;
        float2 p = *(const float2*)(h1b + l2);    // new n1[2l], n1[2l+1]
        asm volatile("" ::: "memory");
        float n2lo = fast_tanh(fmaf(w20, p.x,  fmaf(w21, p.y,  b2)));
        float n2hi = fast_tanh(fmaf(w20, o2.x, fmaf(w21, o2.y, b2)));
        h2b[lane]      = n2lo;
        h2b[lane + 64] = n2hi;
        mlo = fmaxf(mlo, n2lo);
        mhi = fmaxf(mhi, n2hi);
    }

    // ---- Epilogue: linear layer contribution ----
    // mlo is max-pooled feature at flat index k1, mhi at k2 (within qa concat).
    size_t k1 = (size_t)tensor * 16384 + (size_t)lane * 128 + j;
    size_t k2 = k1 + 64 * 128;
    float a0 = fmaf(mlo, lw[k1],         mhi * lw[k2]);
    float a1 = fmaf(mlo, lw[32768 + k1], mhi * lw[32768 + k2]);
    a0 = wave_sum(a0);
    a1 = wave_sum(a1);
    if (lane == 0) {
        atomicAdd(&acc[b * 2 + 0], a0);
        atomicAdd(&acc[b * 2 + 1], a1);
        __threadfence();
    }
    __syncthreads();
    if (threadIdx.x == 0) {
        int c = atomicAdd(counter, 1);
        lastflag = (c == (int)gridDim.x - 1);
    }
    __syncthreads();

    // ---- Last block: bias + log_softmax, write the 32 outputs ----
    if (lastflag && threadIdx.x < 32) {
        int cc = threadIdx.x & 1;
        float s = atomicAdd(&acc[threadIdx.x], 0.0f) + lb[cc];  // L2-coherent read
        float other = __shfl_xor(s, 1, 64);
        float m   = fmaxf(s, other);
        float lse = m + logf(expf(s - m) + expf(other - m));
        out[threadIdx.x] = s - lse;
    }
}

extern "C" void kernel_launch(void* const* d_in, const int* in_sizes, int n_in,
                              void* d_out, int out_size, void* d_ws, size_t ws_size,
                              hipStream_t stream) {
    const int*   q   = (const int*)d_in[0];
    const int*   a   = (const int*)d_in[1];
    const float* emb = (const float*)d_in[2];
    const float* cw  = (const float*)d_in[3];
    const float* cb  = (const float*)d_in[4];
    const float* lw  = (const float*)d_in[5];
    const float* lb  = (const float*)d_in[6];
    float* out = (float*)d_out;

    float* acc     = (float*)d_ws;          // 32 floats
    int*   counter = (int*)(acc + 32);      // 1 int

    hipMemsetAsync(d_ws, 0, 33 * sizeof(float), stream);
    rnn_fused<<<1024, 256, 0, stream>>>(q, a, emb, cw, cb, lw, lb,
                                        acc, counter, out);
}

// Round 4
// 54.255 us; speedup vs baseline: 2.1529x; 2.1529x over previous
//
#include <hip/hip_runtime.h>
#include <math.h>

#define EPS 1e-4f

__device__ __forceinline__ float wave_sum(float v) {
    for (int m = 1; m < 64; m <<= 1)
        v += __shfl_xor(v, m, 64);
    return v;
}

// tanh(x) = 1 - 2/(exp(2x)+1); exp via v_exp_f32, rcp via v_rcp_f32.
// Saturates correctly for large |x| through inf/0 arithmetic.
__device__ __forceinline__ float fast_tanh(float x) {
    float e = __expf(2.0f * x);
    return fmaf(-2.0f, __builtin_amdgcn_rcpf(e + 1.0f), 1.0f);
}

// Fused worker: block = 4 waves = 4 adjacent j for one (tensor, b).
//  Phase A: Y[t][k] = (w0*x[2k]+w1*x[2k+1])/(|x|^2+EPS) into LDS  (x = emb[tok_t])
//  Phase B: XJ[w][t] = emb[tok_t*128 + j_w]
//  Scan: 2-layer strided-conv RNN; state in REGISTERS (lane l owns rows l, l+64
//        of both layers); row gathers h[2l],h[2l+1] via __shfl (ds_bpermute) —
//        no LDS state, no fences.
//  Epilogue: running-max features dotted with lin_w, wave+block reduced,
//        ONE plain store per block to part[blockIdx][2]. No atomics.
__global__ __launch_bounds__(256) void rnn_fused(
    const int* __restrict__ q, const int* __restrict__ a,
    const float* __restrict__ emb, const float* __restrict__ cw,
    const float* __restrict__ cb, const float* __restrict__ lw,
    float* __restrict__ part)
{
    __shared__ float Ylds[64][64];   // 16 KB
    __shared__ float XJ[4][64];      //  1 KB
    __shared__ float red[4][2];

    int w    = threadIdx.x >> 6;
    int lane = threadIdx.x & 63;
    int wid  = blockIdx.x * 4 + w;            // [0,4096)
    int tensor = wid >> 11;
    int b      = (wid >> 7) & 15;
    int j      = wid & 127;
    const int* toks = (tensor ? a : q) + b * 64;
    float w10 = cw[0], w11 = cw[1], b1 = cb[0];
    float w20 = cw[2], w21 = cw[3], b2 = cb[1];

    // ---- Phase A: Y table (wave w: t = w*16 .. w*16+15) ----
    #pragma unroll 4
    for (int i = 0; i < 16; ++i) {
        int t = w * 16 + i;
        int tok = toks[t];
        float2 xv = ((const float2*)(emb + (size_t)tok * 128))[lane];
        float s = wave_sum(fmaf(xv.x, xv.x, xv.y * xv.y)) + EPS;
        Ylds[t][lane] = fmaf(w10, xv.x, w11 * xv.y) * __builtin_amdgcn_rcpf(s);
    }
    // ---- Phase B: xj table ----
    XJ[w][lane] = emb[(size_t)toks[lane] * 128 + j];
    __syncthreads();

    // ---- Main scan: state in registers ----
    int  s0 = (2 * lane) & 63;
    int  s1 = (2 * lane + 1) & 63;
    bool losel = lane < 32;                  // rows 2l,2l+1 < 64 ?
    float h1lo = 0.f, h1hi = 0.f, h2lo = 0.f, h2hi = 0.f;
    float mlo = -1e30f, mhi = -1e30f;
    const float* Yp  = &Ylds[0][lane];
    const float* XJp = &XJ[w][0];

    #pragma unroll 4
    for (int t = 0; t < 64; ++t) {
        float yv = Yp[t * 64];
        float xj = XJp[t];
        // layer-1 old-state gather
        float o1x = losel ? __shfl(h1lo, s0, 64) : __shfl(h1hi, s0, 64);
        float o1y = losel ? __shfl(h1lo, s1, 64) : __shfl(h1hi, s1, 64);
        float n1lo = fast_tanh(fmaf(yv, xj, b1));
        float n1hi = fast_tanh(fmaf(w10, o1x, fmaf(w11, o1y, b1)));
        // layer-2 inputs: NEW layer-1 rows 2l,2l+1, and OLD layer-2 rows
        float px  = losel ? __shfl(n1lo, s0, 64) : __shfl(n1hi, s0, 64);
        float py  = losel ? __shfl(n1lo, s1, 64) : __shfl(n1hi, s1, 64);
        float o2x = losel ? __shfl(h2lo, s0, 64) : __shfl(h2hi, s0, 64);
        float o2y = losel ? __shfl(h2lo, s1, 64) : __shfl(h2hi, s1, 64);
        float n2lo = fast_tanh(fmaf(w20, px,  fmaf(w21, py,  b2)));
        float n2hi = fast_tanh(fmaf(w20, o2x, fmaf(w21, o2y, b2)));
        h1lo = n1lo; h1hi = n1hi; h2lo = n2lo; h2hi = n2hi;
        mlo = fmaxf(mlo, n2lo);
        mhi = fmaxf(mhi, n2hi);
    }

    // ---- Epilogue: linear-layer partial ----
    // mlo = maxpooled feature at qa-flat k1, mhi at k2.
    size_t k1 = (size_t)tensor * 16384 + (size_t)lane * 128 + j;
    size_t k2 = k1 + 64 * 128;
    float a0 = fmaf(mlo, lw[k1],         mhi * lw[k2]);
    float a1 = fmaf(mlo, lw[32768 + k1], mhi * lw[32768 + k2]);
    a0 = wave_sum(a0);
    a1 = wave_sum(a1);
    if (lane == 0) { red[w][0] = a0; red[w][1] = a1; }
    __syncthreads();
    if (threadIdx.x < 2) {
        float s = red[0][threadIdx.x] + red[1][threadIdx.x]
                + red[2][threadIdx.x] + red[3][threadIdx.x];
        part[blockIdx.x * 2 + threadIdx.x] = s;
    }
}

// Final: per (b,c) sum the 64 block-partials (2 tensors x 32 j-groups),
// add bias, log_softmax. One tiny block.
__global__ __launch_bounds__(64) void finalize(
    const float* __restrict__ part, const float* __restrict__ lb,
    float* __restrict__ out)
{
    int tid = threadIdx.x;
    int b = tid >> 1, c = tid & 1;
    float s = 0.f;
    if (tid < 32) {
        s = lb[c];
        #pragma unroll 8
        for (int tg = 0; tg < 64; ++tg) {
            int tensor = tg >> 5, jg = tg & 31;
            s += part[(tensor * 512 + b * 32 + jg) * 2 + c];
        }
    }
    float other = __shfl_xor(s, 1, 64);
    if (tid < 32) {
        float m   = fmaxf(s, other);
        float lse = m + logf(expf(s - m) + expf(other - m));
        out[tid]  = s - lse;
    }
}

extern "C" void kernel_launch(void* const* d_in, const int* in_sizes, int n_in,
                              void* d_out, int out_size, void* d_ws, size_t ws_size,
                              hipStream_t stream) {
    const int*   q   = (const int*)d_in[0];
    const int*   a   = (const int*)d_in[1];
    const float* emb = (const float*)d_in[2];
    const float* cw  = (const float*)d_in[3];
    const float* cb  = (const float*)d_in[4];
    const float* lw  = (const float*)d_in[5];
    const float* lb  = (const float*)d_in[6];
    float* out = (float*)d_out;

    float* part = (float*)d_ws;              // 2048 floats

    rnn_fused<<<1024, 256, 0, stream>>>(q, a, emb, cw, cb, lw, part);
    finalize <<<1,    64,  0, stream>>>(part, lb, out);
}

// Round 5
// 40.048 us; speedup vs baseline: 2.9166x; 1.3547x over previous
//
#include <hip/hip_runtime.h>
#include <math.h>

#define EPS 1e-4f

__device__ __forceinline__ float wave_sum(float v) {
    for (int m = 1; m < 64; m <<= 1)
        v += __shfl_xor(v, m, 64);
    return v;
}

// tanh(x) = 1 - 2/(exp(2x)+1); exp via v_exp_f32, rcp via v_rcp_f32.
// Saturates correctly for large |x| through inf/0 arithmetic.
__device__ __forceinline__ float fast_tanh(float x) {
    float e = __expf(2.0f * x);
    return fmaf(-2.0f, __builtin_amdgcn_rcpf(e + 1.0f), 1.0f);
}

// Fused worker: block = 4 waves = 4 adjacent j for one (tensor, b).
// State in PAIR BASIS registers: E[l] = h[2l], O[l] = h[2l+1].
//   hi rows:   c[m] = tanh(w0*E[m] + w1*O[m] + b)        -- no gather
//   L1 lo rows: recomputed from LDS (ds_read_b64 of y[2l],y[2l+1]) -- no gather
//   L2 lo rows: a2[k] = tanh(w20*E1'[k] + w21*O1'[k] + b2) -- local
//   basis update: 6 bpermutes + 4 cndmask per iteration (was 12 + 6).
__global__ __launch_bounds__(256) void rnn_fused(
    const int* __restrict__ q, const int* __restrict__ a,
    const float* __restrict__ emb, const float* __restrict__ cw,
    const float* __restrict__ cb, const float* __restrict__ lw,
    float* __restrict__ part)
{
    __shared__ __align__(16) float Ylds[64][64];   // 16 KB
    __shared__ float XJ[4][64];                    //  1 KB
    __shared__ float red[4][2];

    int w    = threadIdx.x >> 6;
    int lane = threadIdx.x & 63;
    int wid  = blockIdx.x * 4 + w;            // [0,4096)
    int tensor = wid >> 11;
    int b      = (wid >> 7) & 15;
    int j      = wid & 127;
    const int* toks = (tensor ? a : q) + b * 64;
    float w10 = cw[0], w11 = cw[1], b1 = cb[0];
    float w20 = cw[2], w21 = cw[3], b2 = cb[1];

    // ---- Phase A: Y table (wave w: t = w*16 .. w*16+15) ----
    #pragma unroll 4
    for (int i = 0; i < 16; ++i) {
        int t = w * 16 + i;
        int tok = toks[t];
        float2 xv = ((const float2*)(emb + (size_t)tok * 128))[lane];
        float s = wave_sum(fmaf(xv.x, xv.x, xv.y * xv.y)) + EPS;
        Ylds[t][lane] = fmaf(w10, xv.x, w11 * xv.y) * __builtin_amdgcn_rcpf(s);
    }
    // ---- Phase B: xj table ----
    XJ[w][lane] = emb[(size_t)toks[lane] * 128 + j];
    __syncthreads();

    // ---- Main scan: pair-basis state in registers ----
    int  i0 = (2 * lane) & 63;        // even source index (loop-invariant)
    int  i1 = i0 + 1;                 // odd source index
    bool lo = lane < 32;
    float E1 = 0.f, O1 = 0.f, E2 = 0.f, O2 = 0.f;
    float mE = -1e30f, mO = -1e30f;
    const float*  XJp = &XJ[w][0];
    const float2* Yp2 = (const float2*)(&Ylds[0][0]) + (lane & 31);

    #pragma unroll 4
    for (int t = 0; t < 64; ++t) {
        float  xj = XJp[t];
        float2 yp = Yp2[t * 32];      // y[2l], y[2l+1]  (ds_read_b64)

        // ---- layer 1 ----
        float c1 = fast_tanh(fmaf(w10, E1, fmaf(w11, O1, b1)));   // rows 64..127
        float aE = fast_tanh(fmaf(yp.x, xj, b1));                 // row 2l (lo lanes)
        float aO = fast_tanh(fmaf(yp.y, xj, b1));                 // row 2l+1
        float bE = __shfl(c1, i0, 64);
        float bO = __shfl(c1, i1, 64);
        float E1n = lo ? aE : bE;
        float O1n = lo ? aO : bO;

        // ---- layer 2 ----
        float c2 = fast_tanh(fmaf(w20, E2, fmaf(w21, O2, b2)));   // rows 64..127
        float a2 = fast_tanh(fmaf(w20, E1n, fmaf(w21, O1n, b2))); // rows 0..63 (local!)
        float pE = __shfl(a2, i0, 64);
        float pO = __shfl(a2, i1, 64);
        float qE = __shfl(c2, i0, 64);
        float qO = __shfl(c2, i1, 64);
        float E2n = lo ? pE : qE;
        float O2n = lo ? pO : qO;

        E1 = E1n; O1 = O1n; E2 = E2n; O2 = O2n;
        mE = fmaxf(mE, E2n);          // max over t of h2[2l]
        mO = fmaxf(mO, O2n);          // max over t of h2[2l+1]
    }

    // ---- Epilogue: linear-layer partial (features are rows 2l, 2l+1) ----
    size_t k1 = (size_t)tensor * 16384 + (size_t)(2 * lane) * 128 + j;
    size_t k2 = k1 + 128;
    float a0 = fmaf(mE, lw[k1],         mO * lw[k2]);
    float a1 = fmaf(mE, lw[32768 + k1], mO * lw[32768 + k2]);
    a0 = wave_sum(a0);
    a1 = wave_sum(a1);
    if (lane == 0) { red[w][0] = a0; red[w][1] = a1; }
    __syncthreads();
    if (threadIdx.x < 2) {
        float s = red[0][threadIdx.x] + red[1][threadIdx.x]
                + red[2][threadIdx.x] + red[3][threadIdx.x];
        part[blockIdx.x * 2 + threadIdx.x] = s;
    }
}

// Final: per (b,c) sum the 64 block-partials (2 tensors x 32 j-groups),
// add bias, log_softmax. One tiny block.
__global__ __launch_bounds__(64) void finalize(
    const float* __restrict__ part, const float* __restrict__ lb,
    float* __restrict__ out)
{
    int tid = threadIdx.x;
    int b = tid >> 1, c = tid & 1;
    float s = 0.f;
    if (tid < 32) {
        s = lb[c];
        #pragma unroll 8
        for (int tg = 0; tg < 64; ++tg) {
            int tensor = tg >> 5, jg = tg & 31;
            s += part[(tensor * 512 + b * 32 + jg) * 2 + c];
        }
    }
    float other = __shfl_xor(s, 1, 64);
    if (tid < 32) {
        float m   = fmaxf(s, other);
        float lse = m + logf(expf(s - m) + expf(other - m));
        out[tid]  = s - lse;
    }
}

extern "C" void kernel_launch(void* const* d_in, const int* in_sizes, int n_in,
                              void* d_out, int out_size, void* d_ws, size_t ws_size,
                              hipStream_t stream) {
    const int*   q   = (const int*)d_in[0];
    const int*   a   = (const int*)d_in[1];
    const float* emb = (const float*)d_in[2];
    const float* cw  = (const float*)d_in[3];
    const float* cb  = (const float*)d_in[4];
    const float* lw  = (const float*)d_in[5];
    const float* lb  = (const float*)d_in[6];
    float* out = (float*)d_out;

    float* part = (float*)d_ws;              // 2048 floats

    rnn_fused<<<1024, 256, 0, stream>>>(q, a, emb, cw, cb, lw, part);
    finalize <<<1,    64,  0, stream>>>(part, lb, out);
}

// Round 6
// 39.212 us; speedup vs baseline: 2.9788x; 1.0213x over previous
//
#include <hip/hip_runtime.h>
#include <hip/hip_fp16.h>
#include <math.h>

#define EPS 1e-4f

__device__ __forceinline__ float wave_sum(float v) {
    for (int m = 1; m < 64; m <<= 1)
        v += __shfl_xor(v, m, 64);
    return v;
}

// tanh(x) = 1 - 2/(exp(2x)+1); exp via v_exp_f32, rcp via v_rcp_f32.
// Saturates correctly for large |x| through inf/0 arithmetic.
__device__ __forceinline__ float fast_tanh(float x) {
    float e = __expf(2.0f * x);
    return fmaf(-2.0f, __builtin_amdgcn_rcpf(e + 1.0f), 1.0f);
}

// f16x2 pack/unpack for two-column shuffle transport.
union PkU { __half2 h; int i; };
__device__ __forceinline__ int pk(float a, float b) {
    PkU u; u.h = __floats2half2_rn(a, b); return u.i;
}
__device__ __forceinline__ float pk_lo(int v) { PkU u; u.i = v; return __low2float(u.h); }
__device__ __forceinline__ float pk_hi(int v) { PkU u; u.i = v; return __high2float(u.h); }

// Fused worker. Block = 8 waves = one (tensor,b); wave = column pair (2p, 2p+1).
// Pair-basis state in registers: E[l]=h[2l], O[l]=h[2l+1] per column (A=2p, B=2p+1).
// All inter-lane redistribution is done on f16x2-packed values (one bpermute
// serves both columns): 6 bpermutes + 2 LDS reads per iter per wave = 4 DS/col
// (round 5 was 8/col). Compute stays f32.
__global__ __launch_bounds__(512) void rnn_fused(
    const int* __restrict__ q, const int* __restrict__ a,
    const float* __restrict__ emb, const float* __restrict__ cw,
    const float* __restrict__ cb, const float* __restrict__ lw,
    float* __restrict__ part)
{
    __shared__ __align__(16) float Ylds[64][64];   // 16 KB
    __shared__ float2 XJ[8][64];                   //  4 KB
    __shared__ float red[8][2];

    int w    = threadIdx.x >> 6;              // 0..7
    int lane = threadIdx.x & 63;
    int wid  = blockIdx.x * 8 + w;            // [0,2048)
    int tensor = wid >> 10;
    int b      = (wid >> 6) & 15;
    int p      = wid & 63;                    // column pair: jA=2p, jB=2p+1
    const int* toks = (tensor ? a : q) + b * 64;
    float w10 = cw[0], w11 = cw[1], b1 = cb[0];
    float w20 = cw[2], w21 = cw[3], b2 = cb[1];

    // ---- Phase A: Y table (wave w: rows t = w*8 .. w*8+7) ----
    #pragma unroll 4
    for (int i = 0; i < 8; ++i) {
        int t = w * 8 + i;
        int tok = toks[t];
        float2 xv = ((const float2*)(emb + (size_t)tok * 128))[lane];
        float s = wave_sum(fmaf(xv.x, xv.x, xv.y * xv.y)) + EPS;
        Ylds[t][lane] = fmaf(w10, xv.x, w11 * xv.y) * __builtin_amdgcn_rcpf(s);
    }
    // ---- Phase B: xj table (both columns at once) ----
    XJ[w][lane] = *(const float2*)(emb + (size_t)toks[lane] * 128 + 2 * p);
    __syncthreads();

    // ---- Main scan ----
    int  i0 = (2 * lane) & 63;
    int  i1 = i0 + 1;
    bool lo = lane < 32;
    float E1A = 0.f, O1A = 0.f, E2A = 0.f, O2A = 0.f;
    float E1B = 0.f, O1B = 0.f, E2B = 0.f, O2B = 0.f;
    float mEA = -1e30f, mOA = -1e30f, mEB = -1e30f, mOB = -1e30f;
    const float2* Yp2 = (const float2*)(&Ylds[0][0]) + (lane & 31);
    const float2* XJp = &XJ[w][0];

    #pragma unroll 4
    for (int t = 0; t < 64; ++t) {
        float2 yp = Yp2[t * 32];     // y[2l], y[2l+1] (shared by both columns)
        float2 xj = XJp[t];          // xjA, xjB

        // ---- layer 1 ----
        float cA1 = fast_tanh(fmaf(w10, E1A, fmaf(w11, O1A, b1)));
        float cB1 = fast_tanh(fmaf(w10, E1B, fmaf(w11, O1B, b1)));
        float aEA = fast_tanh(fmaf(yp.x, xj.x, b1));
        float aEB = fast_tanh(fmaf(yp.x, xj.y, b1));
        float aOA = fast_tanh(fmaf(yp.y, xj.x, b1));
        float aOB = fast_tanh(fmaf(yp.y, xj.y, b1));
        int pc1 = pk(cA1, cB1);
        int bE  = __shfl(pc1, i0, 64);
        int bO  = __shfl(pc1, i1, 64);
        int sE1 = lo ? pk(aEA, aEB) : bE;
        int sO1 = lo ? pk(aOA, aOB) : bO;
        float E1An = pk_lo(sE1), E1Bn = pk_hi(sE1);
        float O1An = pk_lo(sO1), O1Bn = pk_hi(sO1);

        // ---- layer 2 ----
        float cA2 = fast_tanh(fmaf(w20, E2A, fmaf(w21, O2A, b2)));
        float cB2 = fast_tanh(fmaf(w20, E2B, fmaf(w21, O2B, b2)));
        float aA2 = fast_tanh(fmaf(w20, E1An, fmaf(w21, O1An, b2)));
        float aB2 = fast_tanh(fmaf(w20, E1Bn, fmaf(w21, O1Bn, b2)));
        int pa2 = pk(aA2, aB2);
        int pc2 = pk(cA2, cB2);
        int pE  = __shfl(pa2, i0, 64);
        int pO  = __shfl(pa2, i1, 64);
        int qE  = __shfl(pc2, i0, 64);
        int qO  = __shfl(pc2, i1, 64);
        int sE2 = lo ? pE : qE;
        int sO2 = lo ? pO : qO;
        float E2An = pk_lo(sE2), E2Bn = pk_hi(sE2);
        float O2An = pk_lo(sO2), O2Bn = pk_hi(sO2);

        E1A = E1An; E1B = E1Bn; O1A = O1An; O1B = O1Bn;
        E2A = E2An; E2B = E2Bn; O2A = O2An; O2B = O2Bn;
        mEA = fmaxf(mEA, E2An); mEB = fmaxf(mEB, E2Bn);
        mOA = fmaxf(mOA, O2An); mOB = fmaxf(mOB, O2Bn);
    }

    // ---- Epilogue: linear-layer partial for both columns ----
    // Column A feature rows 2l,2l+1 at j=2p; column B at j=2p+1.
    size_t k1 = (size_t)tensor * 16384 + (size_t)(2 * lane) * 128 + 2 * p;
    size_t k2 = k1 + 128;
    float a0 = fmaf(mEA, lw[k1], fmaf(mOA, lw[k2],
               fmaf(mEB, lw[k1 + 1], mOB * lw[k2 + 1])));
    float a1 = fmaf(mEA, lw[32768 + k1], fmaf(mOA, lw[32768 + k2],
               fmaf(mEB, lw[32768 + k1 + 1], mOB * lw[32768 + k2 + 1])));
    a0 = wave_sum(a0);
    a1 = wave_sum(a1);
    if (lane == 0) { red[w][0] = a0; red[w][1] = a1; }
    __syncthreads();
    if (threadIdx.x < 2) {
        float s = 0.f;
        #pragma unroll
        for (int i = 0; i < 8; ++i) s += red[i][threadIdx.x];
        part[blockIdx.x * 2 + threadIdx.x] = s;
    }
}

// Final: per (b,c) sum the 16 block-partials (2 tensors x 8 p-groups),
// add bias, log_softmax. One tiny block.
__global__ __launch_bounds__(64) void finalize(
    const float* __restrict__ part, const float* __restrict__ lb,
    float* __restrict__ out)
{
    int tid = threadIdx.x;
    int b = tid >> 1, c = tid & 1;
    float s = 0.f;
    if (tid < 32) {
        s = lb[c];
        #pragma unroll
        for (int tensor = 0; tensor < 2; ++tensor)
            #pragma unroll
            for (int pg = 0; pg < 8; ++pg)
                s += part[((tensor << 7) + b * 8 + pg) * 2 + c];
    }
    float other = __shfl_xor(s, 1, 64);
    if (tid < 32) {
        float m   = fmaxf(s, other);
        float lse = m + logf(expf(s - m) + expf(other - m));
        out[tid]  = s - lse;
    }
}

extern "C" void kernel_launch(void* const* d_in, const int* in_sizes, int n_in,
                              void* d_out, int out_size, void* d_ws, size_t ws_size,
                              hipStream_t stream) {
    const int*   q   = (const int*)d_in[0];
    const int*   a   = (const int*)d_in[1];
    const float* emb = (const float*)d_in[2];
    const float* cw  = (const float*)d_in[3];
    const float* cb  = (const float*)d_in[4];
    const float* lw  = (const float*)d_in[5];
    const float* lb  = (const float*)d_in[6];
    float* out = (float*)d_out;

    float* part = (float*)d_ws;              // 512 floats

    rnn_fused<<<256, 512, 0, stream>>>(q, a, emb, cw, cb, lw, part);
    finalize <<<1,   64,  0, stream>>>(part, lb, out);
}